// Round 6
// baseline (1130.773 us; speedup 1.0000x reference)
//
#include <hip/hip_runtime.h>
#include <cstdint>
#include <cstddef>

// ---------------------------------------------------------------------------
// OppoModelNet: fully-fused per-graph forward (R6 = R4 kernel, clean submit).
// ALL weight matrices and obs/h0 are pre-packed into MFMA-fragment-linear
// layout (frag = 16 cols x 32 k = 512 elems, stored as [lane][8]); every A/B
// fragment load in the fused kernel is a single dense per-wave 1KB load:
// ptr + lane*16B. Removes the 16-line gathers that made R3 latency-bound.
// Packed layout: frag f=(c16<<ksh)+ks holds W[(c16*16+l15)*K + ks*32+l4*8+j]
// at offset f*512 + lane*8 + j   (K = 32<<ksh).
// ---------------------------------------------------------------------------

#define NN 65536
#define NE 524288

typedef __bf16 bf16x8 __attribute__((ext_vector_type(8)));
typedef float  f32x4  __attribute__((ext_vector_type(4)));

__device__ __forceinline__ float bf2f(unsigned short u){
  union { unsigned int i; float f; } v; v.i = ((unsigned int)u) << 16; return v.f;
}
__device__ __forceinline__ unsigned short f2b(float f){
  union { float f; unsigned int i; } v; v.f = f;
  unsigned int r = v.i + 0x7FFFu + ((v.i >> 16) & 1u);
  return (unsigned short)(r >> 16);
}
__device__ __forceinline__ float sigm(float x){ return 1.f/(1.f+__expf(-x)); }

// ---------------------------------------------------------------------------
// pack fp32 [Nc][K] row-major -> bf16 fragment-linear (K = 32<<kshift)
// ---------------------------------------------------------------------------
struct PackArgs {
  const float* s[14];
  unsigned short* d[14];
  int n8[14];      // total elems / 8
  int ksh[14];     // log2(K/32)
  int cnt;
};

__global__ __launch_bounds__(256) void pack_kernel(PackArgs a){
  int stride = gridDim.x * blockDim.x;
  int gid0 = blockIdx.x * blockDim.x + threadIdx.x;
  for (int seg = 0; seg < a.cnt; ++seg){
    const float* s = a.s[seg];
    unsigned short* d = a.d[seg];
    int n8 = a.n8[seg], ksh = a.ksh[seg];
    int K = 32 << ksh, kmask = (1 << ksh) - 1;
    for (int gid = gid0; gid < n8; gid += stride){
      int f = gid >> 6, l = gid & 63;
      int c16 = f >> ksh, ks = f & kmask;
      size_t soff = (size_t)((c16 << 4) + (l & 15)) * K + (ks << 5) + ((l >> 4) << 3);
      float4 v0 = *(const float4*)(s + soff);
      float4 v1 = *(const float4*)(s + soff + 4);
      ushort4 o0, o1;
      o0.x=f2b(v0.x); o0.y=f2b(v0.y); o0.z=f2b(v0.z); o0.w=f2b(v0.w);
      o1.x=f2b(v1.x); o1.y=f2b(v1.y); o1.z=f2b(v1.z); o1.w=f2b(v1.w);
      *(ushort4*)(d + (size_t)gid * 8)     = o0;
      *(ushort4*)(d + (size_t)gid * 8 + 4) = o1;
    }
  }
}

// ---------------------------------------------------------------------------
// counting sort by dst: hist -> scan -> scatter
// ---------------------------------------------------------------------------
__global__ __launch_bounds__(256) void hist_kernel(
    const int* __restrict__ dst, int* __restrict__ hist)
{
  int e = blockIdx.x * 256 + threadIdx.x;
  atomicAdd(&hist[dst[e]], 1);
}

__global__ __launch_bounds__(256) void scan1_kernel(
    const int* __restrict__ hist, int* __restrict__ offs, int* __restrict__ bsum)
{
  __shared__ int s[256];
  int b = blockIdx.x, t = threadIdx.x;
  int v = hist[b * 256 + t];
  s[t] = v; __syncthreads();
  for (int d = 1; d < 256; d <<= 1){
    int x = (t >= d) ? s[t - d] : 0;
    __syncthreads();
    s[t] += x;
    __syncthreads();
  }
  offs[b * 256 + t] = s[t] - v;
  if (t == 255) bsum[b] = s[255];
}

__global__ __launch_bounds__(256) void scan2_kernel(int* __restrict__ bsum){
  __shared__ int s[256];
  int t = threadIdx.x;
  int v = bsum[t];
  s[t] = v; __syncthreads();
  for (int d = 1; d < 256; d <<= 1){
    int x = (t >= d) ? s[t - d] : 0;
    __syncthreads();
    s[t] += x;
    __syncthreads();
  }
  bsum[t] = s[t] - v;
}

__global__ __launch_bounds__(256) void scan3_kernel(
    int* __restrict__ offs, const int* __restrict__ bsum, int* __restrict__ cursor)
{
  int i = blockIdx.x * 256 + threadIdx.x;
  int v = offs[i] + bsum[blockIdx.x];
  offs[i] = v;
  cursor[i] = v;
}

__global__ __launch_bounds__(256) void scatter_kernel(
    const int* __restrict__ src, const int* __restrict__ dst,
    int* __restrict__ cursor, int* __restrict__ sorted_src)
{
  int e = blockIdx.x * 256 + threadIdx.x;
  int d = dst[e];
  int pos = atomicAdd(&cursor[d], 1);
  sorted_src[pos] = src[e];
}

// ---------------------------------------------------------------------------
// the mega kernel: one block = one 128-node graph, 512 threads = 8 waves (2x4)
// LDS pool aliasing (u16 elem offsets):
//   [0,32768)      X(TF256) -> NF(TF128)@[0,16K) -> nf2(TF128)
//   [16384,32768)  P_half(RM) -> AGG(TF128)
//   [32768,65536)  ychunk(TF128)@[32K,49K) -> RB(TF256) -> Q(RM)@[32K,49K)
//                  + Hsum(TF128)@[49K,65K) -> hidn(TF256) -> rh(TF256)
// ---------------------------------------------------------------------------
#define POOL_X   0
#define POOL_NF  0
#define POOL_NF2 0
#define POOL_P   16384
#define POOL_AGG 16384
#define POOL_YC  32768
#define POOL_RB  32768
#define POOL_Q   32768
#define POOL_HS  49152
#define POOL_HID 32768
#define POOL_RH  32768

__global__ __launch_bounds__(512, 2) void fused_kernel(
    const unsigned short* __restrict__ obs_p,  // packed frag-linear K=256
    const unsigned short* __restrict__ h0_p,   // packed frag-linear K=256
    const float* __restrict__ c0,              // [N][256] fp32
    const unsigned short* __restrict__ w1a_p,  // packed [512]x[256]
    const float* __restrict__ b1a,
    const unsigned short* __restrict__ w1b_p,  // packed [256]x[512]
    const float* __restrict__ b1b,
    const unsigned short* __restrict__ wih_p,  // packed [1024]x[256]
    const unsigned short* __restrict__ whh_p,  // packed [1024]x[256]
    const float* __restrict__ b_ih, const float* __restrict__ b_hh,
    const unsigned short* __restrict__ w1_p,   // packed [128]x[256]
    const float* __restrict__ b1,
    const unsigned short* __restrict__ we_p,   // packed [256]x[256]
    const float* __restrict__ be,
    const unsigned short* __restrict__ we2_p,  // packed [128]x[256]
    const float* __restrict__ be2,
    const unsigned short* __restrict__ wn_p,   // packed [256]x[256]
    const float* __restrict__ bn,
    const unsigned short* __restrict__ wn2_p,  // packed [128]x[256]
    const float* __restrict__ bn2,
    const unsigned short* __restrict__ wr_p,   // packed [256]x[128]
    const float* __restrict__ br,
    const float* __restrict__ wr2,             // fp32 [8][256]
    const float* __restrict__ br2,
    const int* __restrict__ hist, const int* __restrict__ offs,
    const int* __restrict__ ssrc,
    float* __restrict__ logits, float* __restrict__ h1o, float* __restrict__ c1o)
{
  __shared__ alignas(16) unsigned short pool[65536];   // 128 KB

  int tid = threadIdx.x;
  int w = tid >> 6, lane = tid & 63;
  int wr = w >> 2, wc = w & 3;           // 2 x 4 wave grid
  int l15 = lane & 15, l4 = lane >> 4;
  int g = blockIdx.x;
  int gbase = g << 7;
  int lofs = lane << 3;

  // --- packed-global frag loaders (dense 16B/lane) ---
  // A from packed node-features (K=256, ksh=3): row16 = g*8 + rt
  auto ldA_gp = [&](const unsigned short* base, int rt, int ks) -> bf16x8 {
    return *(const bf16x8*)(base + ((size_t)(((g << 3) + rt) << 3) + ks) * 512 + lofs);
  };
  // B from packed weights: frag = ((n0>>4)<<ksh) + ks
  auto ldBp = [&](const unsigned short* W, int ksh, int n0, int ks) -> bf16x8 {
    return *(const bf16x8*)(W + ((size_t)(((n0 >> 4) << ksh) + ks) << 9) + lofs);
  };
  // --- LDS TF-layout frag loaders / scalar stores ---
  auto ldA_tf256 = [&](int base, int rt, int ks) -> bf16x8 {
    return *(const bf16x8*)&pool[base + (rt << 12) + (((ks << 2) + l4) << 7) + (l15 << 3)];
  };
  auto ldA_tf128 = [&](int base, int rt, int ks) -> bf16x8 {
    return *(const bf16x8*)&pool[base + (rt << 11) + (((ks << 2) + l4) << 7) + (l15 << 3)];
  };
  auto stTF256 = [&](int base, int row, int col, unsigned short v){
    pool[base + ((row >> 4) << 12) + ((col >> 3) << 7) + ((row & 15) << 3) + (col & 7)] = v;
  };
  auto stTF128 = [&](int base, int row, int col, unsigned short v){
    pool[base + ((row >> 4) << 11) + ((col >> 3) << 7) + ((row & 15) << 3) + (col & 7)] = v;
  };

  // ===== stage 1+2: y1 = relu(obs@w1a^T+b1a) chunked; x = y1@w1b^T+b1b =====
  {
    f32x4 xacc[2][4][2] = {};
    for (int c = 0; c < 4; ++c){
      f32x4 yacc[4][2] = {};
#pragma unroll
      for (int ks = 0; ks < 8; ++ks){
        bf16x8 a[4];
#pragma unroll
        for (int m = 0; m < 4; ++m) a[m] = ldA_gp(obs_p, (wr << 2) + m, ks);
#pragma unroll
        for (int n = 0; n < 2; ++n){
          bf16x8 b = ldBp(w1a_p, 3, c * 128 + (wc << 5) + (n << 4), ks);
#pragma unroll
          for (int m = 0; m < 4; ++m)
            yacc[m][n] = __builtin_amdgcn_mfma_f32_16x16x32_bf16(a[m], b, yacc[m][n], 0, 0, 0);
        }
      }
#pragma unroll
      for (int n = 0; n < 2; ++n){
        float bv = b1a[c * 128 + (wc << 5) + (n << 4) + l15];
#pragma unroll
        for (int m = 0; m < 4; ++m)
#pragma unroll
          for (int r = 0; r < 4; ++r){
            int row = (wr << 6) + (m << 4) + (l4 << 2) + r;
            int col = (wc << 5) + (n << 4) + l15;
            stTF128(POOL_YC, row, col, f2b(fmaxf(yacc[m][n][r] + bv, 0.f)));
          }
      }
      __syncthreads();
#pragma unroll
      for (int ks = 0; ks < 4; ++ks){
        bf16x8 a[4];
#pragma unroll
        for (int m = 0; m < 4; ++m) a[m] = ldA_tf128(POOL_YC, (wr << 2) + m, ks);
#pragma unroll
        for (int nt = 0; nt < 2; ++nt)
#pragma unroll
          for (int n = 0; n < 2; ++n){
            bf16x8 b = ldBp(w1b_p, 4, nt * 128 + (wc << 5) + (n << 4), c * 4 + ks);
#pragma unroll
            for (int m = 0; m < 4; ++m)
              xacc[nt][m][n] = __builtin_amdgcn_mfma_f32_16x16x32_bf16(a[m], b, xacc[nt][m][n], 0, 0, 0);
          }
      }
      __syncthreads();  // before ychunk overwrite
    }
#pragma unroll
    for (int nt = 0; nt < 2; ++nt)
#pragma unroll
      for (int n = 0; n < 2; ++n){
        int col = nt * 128 + (wc << 5) + (n << 4) + l15;
        float bv = b1b[col];
#pragma unroll
        for (int m = 0; m < 4; ++m)
#pragma unroll
          for (int r = 0; r < 4; ++r){
            int row = (wr << 6) + (m << 4) + (l4 << 2) + r;
            stTF256(POOL_X, row, col, f2b(xacc[nt][m][n][r] + bv));
          }
      }
  }
  __syncthreads();

  // ===== stage 3: gates + LSTM -> h1o, c1o, RB(=relu(h1)) =====
  for (int cc = 0; cc < 2; ++cc){
    f32x4 gacc[4][4][2] = {};   // [gate][m][n]
#pragma unroll
    for (int ks = 0; ks < 16; ++ks){
      bf16x8 a[4];
      const unsigned short* Wb;
      int krel;
      if (ks < 8){
#pragma unroll
        for (int m = 0; m < 4; ++m) a[m] = ldA_tf256(POOL_X, (wr << 2) + m, ks);
        Wb = wih_p; krel = ks;
      } else {
#pragma unroll
        for (int m = 0; m < 4; ++m) a[m] = ldA_gp(h0_p, (wr << 2) + m, ks - 8);
        Wb = whh_p; krel = ks - 8;
      }
#pragma unroll
      for (int gg = 0; gg < 4; ++gg)
#pragma unroll
        for (int n = 0; n < 2; ++n){
          bf16x8 b = ldBp(Wb, 3, gg * 256 + cc * 128 + (wc << 5) + (n << 4), krel);
#pragma unroll
          for (int m = 0; m < 4; ++m)
            gacc[gg][m][n] = __builtin_amdgcn_mfma_f32_16x16x32_bf16(a[m], b, gacc[gg][m][n], 0, 0, 0);
        }
    }
#pragma unroll
    for (int n = 0; n < 2; ++n){
      int col = cc * 128 + (wc << 5) + (n << 4) + l15;
      float bi  = b_ih[col]       + b_hh[col];
      float bff = b_ih[256 + col] + b_hh[256 + col];
      float bg  = b_ih[512 + col] + b_hh[512 + col];
      float bo  = b_ih[768 + col] + b_hh[768 + col];
#pragma unroll
      for (int m = 0; m < 4; ++m)
#pragma unroll
        for (int r = 0; r < 4; ++r){
          int row = (wr << 6) + (m << 4) + (l4 << 2) + r;
          size_t off = (size_t)(gbase + row) * 256 + col;
          float iv = sigm(gacc[0][m][n][r] + bi);
          float fv = sigm(gacc[1][m][n][r] + bff);
          float gv = tanhf(gacc[2][m][n][r] + bg);
          float ov = sigm(gacc[3][m][n][r] + bo);
          float cv = fv * c0[off] + iv * gv;
          float hv = ov * tanhf(cv);
          h1o[off] = hv;
          c1o[off] = cv;
          stTF256(POOL_RB, row, col, f2b(fmaxf(hv, 0.f)));
        }
    }
  }
  __syncthreads();

  // ===== stage 4: nf = RB @ w1^T + b1 -> NF (TF128) =====
  {
    f32x4 acc[4][2] = {};
#pragma unroll
    for (int ks = 0; ks < 8; ++ks){
      bf16x8 a[4];
#pragma unroll
      for (int m = 0; m < 4; ++m) a[m] = ldA_tf256(POOL_RB, (wr << 2) + m, ks);
#pragma unroll
      for (int n = 0; n < 2; ++n){
        bf16x8 b = ldBp(w1_p, 3, (wc << 5) + (n << 4), ks);
#pragma unroll
        for (int m = 0; m < 4; ++m)
          acc[m][n] = __builtin_amdgcn_mfma_f32_16x16x32_bf16(a[m], b, acc[m][n], 0, 0, 0);
      }
    }
#pragma unroll
    for (int n = 0; n < 2; ++n){
      int col = (wc << 5) + (n << 4) + l15;
      float bv = b1[col];
#pragma unroll
      for (int m = 0; m < 4; ++m)
#pragma unroll
        for (int r = 0; r < 4; ++r){
          int row = (wr << 6) + (m << 4) + (l4 << 2) + r;
          stTF128(POOL_NF, row, col, f2b(acc[m][n][r] + bv));
        }
    }
  }
  __syncthreads();

  // ===== stages 5-7: edge MLP halves + aggregation + agg GEMM =====
  f32x4 agg_acc[4][2] = {};
  for (int h = 0; h < 2; ++h){
    {  // P_h = NF@we_L[h]^T ; Q_h = NF@we_R[h]^T + be_h   (row-major out)
      f32x4 pacc[4][2] = {}, qacc[4][2] = {};
#pragma unroll
      for (int ks = 0; ks < 4; ++ks){
        bf16x8 a[4];
#pragma unroll
        for (int m = 0; m < 4; ++m) a[m] = ldA_tf128(POOL_NF, (wr << 2) + m, ks);
#pragma unroll
        for (int n = 0; n < 2; ++n){
          bf16x8 bp = ldBp(we_p, 3, h * 128 + (wc << 5) + (n << 4), ks);
          bf16x8 bq = ldBp(we_p, 3, h * 128 + (wc << 5) + (n << 4), ks + 4);
#pragma unroll
          for (int m = 0; m < 4; ++m){
            pacc[m][n] = __builtin_amdgcn_mfma_f32_16x16x32_bf16(a[m], bp, pacc[m][n], 0, 0, 0);
            qacc[m][n] = __builtin_amdgcn_mfma_f32_16x16x32_bf16(a[m], bq, qacc[m][n], 0, 0, 0);
          }
        }
      }
#pragma unroll
      for (int n = 0; n < 2; ++n){
        int col = (wc << 5) + (n << 4) + l15;
        float bv = be[h * 128 + col];
#pragma unroll
        for (int m = 0; m < 4; ++m)
#pragma unroll
          for (int r = 0; r < 4; ++r){
            int row = (wr << 6) + (m << 4) + (l4 << 2) + r;
            pool[POOL_P + row * 128 + col] = f2b(pacc[m][n][r]);
            pool[POOL_Q + row * 128 + col] = f2b(qacc[m][n][r] + bv);
          }
      }
    }
    __syncthreads();
    {  // edge aggregation: Hsum_h[n] = sum relu(P[src]+Q[n])
      int hl = lane >> 5, ll = lane & 31;
      int d0 = ll << 2;
#pragma unroll 1
      for (int pass = 0; pass < 8; ++pass){
        int ln = (pass << 4) + (w << 1) + hl;
        int ng = gbase + ln;
        int eoff = offs[ng], ecnt = hist[ng];
        unsigned long long qv = *(const unsigned long long*)&pool[POOL_Q + ln * 128 + d0];
        float q0 = bf2f((unsigned short)qv);
        float q1 = bf2f((unsigned short)(qv >> 16));
        float q2 = bf2f((unsigned short)(qv >> 32));
        float q3 = bf2f((unsigned short)(qv >> 48));
        float s0 = 0.f, s1 = 0.f, s2 = 0.f, s3 = 0.f;
        for (int i = 0; i < ecnt; ++i){
          int s = ssrc[eoff + i] - gbase;
          unsigned long long pv = *(const unsigned long long*)&pool[POOL_P + s * 128 + d0];
          s0 += fmaxf(bf2f((unsigned short)pv) + q0, 0.f);
          s1 += fmaxf(bf2f((unsigned short)(pv >> 16)) + q1, 0.f);
          s2 += fmaxf(bf2f((unsigned short)(pv >> 32)) + q2, 0.f);
          s3 += fmaxf(bf2f((unsigned short)(pv >> 48)) + q3, 0.f);
        }
        unsigned long long hv = (unsigned long long)f2b(s0)
                              | ((unsigned long long)f2b(s1) << 16)
                              | ((unsigned long long)f2b(s2) << 32)
                              | ((unsigned long long)f2b(s3) << 48);
        *(unsigned long long*)&pool[POOL_HS + ((ln >> 4) << 11) + ((d0 >> 3) << 7) + ((ln & 15) << 3) + (d0 & 7)] = hv;
      }
    }
    __syncthreads();
    // agg_acc += Hsum_h @ we2[:, h*128..]^T
#pragma unroll
    for (int ks = 0; ks < 4; ++ks){
      bf16x8 a[4];
#pragma unroll
      for (int m = 0; m < 4; ++m) a[m] = ldA_tf128(POOL_HS, (wr << 2) + m, ks);
#pragma unroll
      for (int n = 0; n < 2; ++n){
        bf16x8 b = ldBp(we2_p, 3, (wc << 5) + (n << 4), h * 4 + ks);
#pragma unroll
        for (int m = 0; m < 4; ++m)
          agg_acc[m][n] = __builtin_amdgcn_mfma_f32_16x16x32_bf16(a[m], b, agg_acc[m][n], 0, 0, 0);
      }
    }
    __syncthreads();  // before next h overwrites P/Q/HS
  }
#pragma unroll
  for (int n = 0; n < 2; ++n){
    int col = (wc << 5) + (n << 4) + l15;
    float bv = be2[col];
#pragma unroll
    for (int m = 0; m < 4; ++m)
#pragma unroll
      for (int r = 0; r < 4; ++r){
        int row = (wr << 6) + (m << 4) + (l4 << 2) + r;
        float dv = (float)hist[gbase + row];
        stTF128(POOL_AGG, row, col, f2b(agg_acc[m][n][r] + bv * dv));
      }
  }
  __syncthreads();

  // ===== stage 8: hidn = relu([NF|AGG] @ wn^T + bn) -> HID (TF256) =====
  {
    f32x4 hacc[2][4][2] = {};
#pragma unroll
    for (int ks = 0; ks < 8; ++ks){
      bf16x8 a[4];
      if (ks < 4){
#pragma unroll
        for (int m = 0; m < 4; ++m) a[m] = ldA_tf128(POOL_NF, (wr << 2) + m, ks);
      } else {
#pragma unroll
        for (int m = 0; m < 4; ++m) a[m] = ldA_tf128(POOL_AGG, (wr << 2) + m, ks - 4);
      }
#pragma unroll
      for (int nt = 0; nt < 2; ++nt)
#pragma unroll
        for (int n = 0; n < 2; ++n){
          bf16x8 b = ldBp(wn_p, 3, nt * 128 + (wc << 5) + (n << 4), ks);
#pragma unroll
          for (int m = 0; m < 4; ++m)
            hacc[nt][m][n] = __builtin_amdgcn_mfma_f32_16x16x32_bf16(a[m], b, hacc[nt][m][n], 0, 0, 0);
        }
    }
    __syncthreads();
#pragma unroll
    for (int nt = 0; nt < 2; ++nt)
#pragma unroll
      for (int n = 0; n < 2; ++n){
        int col = nt * 128 + (wc << 5) + (n << 4) + l15;
        float bv = bn[col];
#pragma unroll
        for (int m = 0; m < 4; ++m)
#pragma unroll
          for (int r = 0; r < 4; ++r){
            int row = (wr << 6) + (m << 4) + (l4 << 2) + r;
            stTF256(POOL_HID, row, col, f2b(fmaxf(hacc[nt][m][n][r] + bv, 0.f)));
          }
      }
  }
  __syncthreads();

  // ===== stage 9: nf2 = HID @ wn2^T + bn2 -> NF2 (TF128 @0) =====
  {
    f32x4 acc[4][2] = {};
#pragma unroll
    for (int ks = 0; ks < 8; ++ks){
      bf16x8 a[4];
#pragma unroll
      for (int m = 0; m < 4; ++m) a[m] = ldA_tf256(POOL_HID, (wr << 2) + m, ks);
#pragma unroll
      for (int n = 0; n < 2; ++n){
        bf16x8 b = ldBp(wn2_p, 3, (wc << 5) + (n << 4), ks);
#pragma unroll
        for (int m = 0; m < 4; ++m)
          acc[m][n] = __builtin_amdgcn_mfma_f32_16x16x32_bf16(a[m], b, acc[m][n], 0, 0, 0);
      }
    }
    __syncthreads();
#pragma unroll
    for (int n = 0; n < 2; ++n){
      int col = (wc << 5) + (n << 4) + l15;
      float bv = bn2[col];
#pragma unroll
      for (int m = 0; m < 4; ++m)
#pragma unroll
        for (int r = 0; r < 4; ++r){
          int row = (wr << 6) + (m << 4) + (l4 << 2) + r;
          stTF128(POOL_NF2, row, col, f2b(acc[m][n][r] + bv));
        }
    }
  }
  __syncthreads();

  // ===== stage 10: rh = relu(NF2 @ wr^T + br) -> RH (TF256) =====
  {
    f32x4 racc[2][4][2] = {};
#pragma unroll
    for (int ks = 0; ks < 4; ++ks){
      bf16x8 a[4];
#pragma unroll
      for (int m = 0; m < 4; ++m) a[m] = ldA_tf128(POOL_NF2, (wr << 2) + m, ks);
#pragma unroll
      for (int nt = 0; nt < 2; ++nt)
#pragma unroll
        for (int n = 0; n < 2; ++n){
          bf16x8 b = ldBp(wr_p, 2, nt * 128 + (wc << 5) + (n << 4), ks);
#pragma unroll
          for (int m = 0; m < 4; ++m)
            racc[nt][m][n] = __builtin_amdgcn_mfma_f32_16x16x32_bf16(a[m], b, racc[nt][m][n], 0, 0, 0);
        }
    }
    __syncthreads();
#pragma unroll
    for (int nt = 0; nt < 2; ++nt)
#pragma unroll
      for (int n = 0; n < 2; ++n){
        int col = nt * 128 + (wc << 5) + (n << 4) + l15;
        float bv = br[col];
#pragma unroll
        for (int m = 0; m < 4; ++m)
#pragma unroll
          for (int r = 0; r < 4; ++r){
            int row = (wr << 6) + (m << 4) + (l4 << 2) + r;
            stTF256(POOL_RH, row, col, f2b(fmaxf(racc[nt][m][n][r] + bv, 0.f)));
          }
      }
  }
  __syncthreads();

  // ===== stage 11: logits = RH @ wr2^T + br2 (fp32 out) =====
  {
    int node = tid >> 2, q = tid & 3;
    int o0 = q << 1;
    float s0 = br2[o0], s1 = br2[o0 + 1];
    const float* w0 = wr2 + (size_t)o0 * 256;
    const float* w1 = w0 + 256;
#pragma unroll
    for (int kc = 0; kc < 32; ++kc){
      const unsigned short* rp = &pool[POOL_RH + ((node >> 4) << 12) + (kc << 7) + ((node & 15) << 3)];
      const float* wp0 = w0 + kc * 8;
      const float* wp1 = w1 + kc * 8;
#pragma unroll
      for (int i = 0; i < 8; ++i){
        float rv = bf2f(rp[i]);
        s0 += rv * bf2f(f2b(wp0[i]));
        s1 += rv * bf2f(f2b(wp1[i]));
      }
    }
    size_t ob = (size_t)(gbase + node) * 8 + o0;
    logits[ob] = s0;
    logits[ob + 1] = s1;
  }
}

// ---------------------------------------------------------------------------
extern "C" void kernel_launch(void* const* d_in, const int* in_sizes, int n_in,
                              void* d_out, int out_size, void* d_ws, size_t ws_size,
                              hipStream_t stream)
{
  (void)in_sizes; (void)n_in; (void)out_size; (void)ws_size;
  const float* obs = (const float*)d_in[0];
  const float* h0  = (const float*)d_in[1];
  const float* c0  = (const float*)d_in[2];
  const int*   src = (const int*)d_in[3];
  const int*   dst = (const int*)d_in[4];
  const float* w1a = (const float*)d_in[5];
  const float* b1a = (const float*)d_in[6];
  const float* w1b = (const float*)d_in[7];
  const float* b1b = (const float*)d_in[8];
  const float* wih = (const float*)d_in[9];
  const float* bih = (const float*)d_in[10];
  const float* whh = (const float*)d_in[11];
  const float* bhh = (const float*)d_in[12];
  const float* w1  = (const float*)d_in[13];
  const float* b1  = (const float*)d_in[14];
  const float* we  = (const float*)d_in[15];
  const float* be  = (const float*)d_in[16];
  const float* we2 = (const float*)d_in[17];
  const float* be2 = (const float*)d_in[18];
  const float* wn  = (const float*)d_in[19];
  const float* bn  = (const float*)d_in[20];
  const float* wn2 = (const float*)d_in[21];
  const float* bn2 = (const float*)d_in[22];
  const float* wr  = (const float*)d_in[23];
  const float* br  = (const float*)d_in[24];
  const float* wr2 = (const float*)d_in[25];
  const float* br2 = (const float*)d_in[26];

  char* ws = (char*)d_ws;
  typedef unsigned short u16;
  u16* w1a_p = (u16*)(ws + 0);
  u16* w1b_p = (u16*)(ws + 262144);
  u16* wih_p = (u16*)(ws + 524288);
  u16* whh_p = (u16*)(ws + 1048576);
  u16* w1_p  = (u16*)(ws + 1572864);
  u16* we_p  = (u16*)(ws + 1638400);
  u16* we2_p = (u16*)(ws + 1769472);
  u16* wn_p  = (u16*)(ws + 1835008);
  u16* wn2_p = (u16*)(ws + 1966080);
  u16* wr_p  = (u16*)(ws + 2031616);
  int* hist    = (int*)(ws + 2103296);          // [65536] = deg
  int* offs    = (int*)(ws + 2365440);          // [65536]
  int* cursor  = (int*)(ws + 2627584);          // [65536]
  int* bsum    = (int*)(ws + 2889728);          // [256]
  int* ssrc    = (int*)(ws + 2890752);          // sorted_src [524288]

  u16* obs_p = (u16*)(ws + 5242880);            // packed [N]x[256] bf16
  u16* h0_p  = (u16*)(ws + 38797312);           // packed [N]x[256] bf16

  float* logits = (float*)d_out;
  float* h1o = logits + (size_t)NN * 8;
  float* c1o = h1o + (size_t)NN * 256;

  // 0) zero hist
  (void)hipMemsetAsync(hist, 0, 65536 * 4, stream);

  // 1) pack fp32 -> bf16 fragment-linear (weights + obs + h0)
  PackArgs pa;
  const float* ss[12] = {obs, h0, w1a, w1b, wih, whh, w1, we, we2, wn, wn2, wr};
  u16* dd[12] = {obs_p, h0_p, w1a_p, w1b_p, wih_p, whh_p, w1_p, we_p, we2_p, wn_p, wn2_p, wr_p};
  int ne[12] = {NN*256, NN*256, 512*256, 256*512, 1024*256, 1024*256, 128*256,
                256*256, 128*256, 256*256, 128*256, 256*128};
  int kk[12] = {3, 3, 3, 4, 3, 3, 3, 3, 3, 3, 3, 2};  // log2(K/32)
  for (int i = 0; i < 12; ++i){ pa.s[i]=ss[i]; pa.d[i]=dd[i]; pa.n8[i]=ne[i]/8; pa.ksh[i]=kk[i]; }
  pa.cnt = 12;
  pack_kernel<<<2048, 256, 0, stream>>>(pa);

  // 2) counting sort of edges by dst
  hist_kernel<<<NE/256, 256, 0, stream>>>(dst, hist);
  scan1_kernel<<<256, 256, 0, stream>>>(hist, offs, bsum);
  scan2_kernel<<<1, 256, 0, stream>>>(bsum);
  scan3_kernel<<<256, 256, 0, stream>>>(offs, bsum, cursor);
  scatter_kernel<<<NE/256, 256, 0, stream>>>(src, dst, cursor, ssrc);

  // 3) the whole network, one block per graph
  fused_kernel<<<NN/128, 512, 0, stream>>>(
      obs_p, h0_p, c0,
      w1a_p, b1a, w1b_p, b1b,
      wih_p, whh_p, bih, bhh,
      w1_p, b1,
      we_p, be, we2_p, be2,
      wn_p, bn, wn2_p, bn2,
      wr_p, br, wr2, br2,
      hist, offs, ssrc,
      logits, h1o, c1o);
}

// Round 7
// 907.409 us; speedup vs baseline: 1.2462x; 1.2462x over previous
//
#include <hip/hip_runtime.h>
#include <cstdint>
#include <cstddef>

// ---------------------------------------------------------------------------
// OppoModelNet: GNN forward (R7 = R2 structure + T4 counted-vmcnt pipeline).
//   encoder (256->512->256) -> LSTM step (256) -> nf (128)
//   edge MLP via linear split: P=nf@we_L^T, Q=nf@we_R^T+be,
//     Hsum[n] = sum_{e:dst=n} relu(P[src_e]+Q[n])   (counting-sorted, no atomics)
//     agg = Hsum@we2^T + deg*be2
//   node MLP (256->256->128) -> readout (128->256->8)
// GEMM K-loops: double-buffered global_load_lds with COUNTED vmcnt (never 0
// in the loop) + raw s_barrier, so next-tile DMAs stay in flight across the
// barrier while current tile computes (T3/T4 from the technique catalog).
// ---------------------------------------------------------------------------

#define NN 65536      // nodes
#define NE 524288     // edges

typedef __bf16 bf16x8 __attribute__((ext_vector_type(8)));
typedef float  f32x4  __attribute__((ext_vector_type(4)));

typedef __attribute__((address_space(1))) unsigned int glb_uint;
typedef __attribute__((address_space(3))) unsigned int lds_uint;

__device__ __forceinline__ void async16(const void* g, void* l){
  __builtin_amdgcn_global_load_lds((glb_uint*)g, (lds_uint*)l, 16, 0, 0);
}

__device__ __forceinline__ float bf2f(unsigned short u){
  union { unsigned int i; float f; } v; v.i = ((unsigned int)u) << 16; return v.f;
}
__device__ __forceinline__ unsigned short f2b(float f){
  union { float f; unsigned int i; } v; v.f = f;
  unsigned int r = v.i + 0x7FFFu + ((v.i >> 16) & 1u);
  return (unsigned short)(r >> 16);
}
__device__ __forceinline__ float sigm(float x){ return 1.f/(1.f+__expf(-x)); }

// ---------------------------------------------------------------------------
// batched fp32 -> bf16 conversion
// ---------------------------------------------------------------------------
struct ConvArgs {
  const float* s[14];
  unsigned short* d[14];
  int n4[14];
  int cnt;
};

__global__ __launch_bounds__(256) void convert_kernel(ConvArgs a){
  int stride = gridDim.x * blockDim.x;
  int gid = blockIdx.x * blockDim.x + threadIdx.x;
  for (int seg = 0; seg < a.cnt; ++seg){
    const float4* s = (const float4*)a.s[seg];
    ushort4* d = (ushort4*)a.d[seg];
    int n4 = a.n4[seg];
    for (int i = gid; i < n4; i += stride){
      float4 v = s[i];
      ushort4 o; o.x=f2b(v.x); o.y=f2b(v.y); o.z=f2b(v.z); o.w=f2b(v.w);
      d[i] = o;
    }
  }
}

// ---------------------------------------------------------------------------
// generic bf16 GEMM: C[M,Nc] = act(A[M,K] @ B[Nc,K]^T + bias), bf16 out
// 128x128 tile, BK=32, 256 threads = 4 waves (2x2), wave tile 64x64.
// Pipeline per K-step: stage(next buf: 4 DMAs) -> vmcnt(4) [prev buf's loads
// done; new 4 still flying] -> s_barrier -> ds_read+MFMA(cur) -> lgkmcnt(0)
// -> s_barrier -> swap. DMAs overlap MFMA; no vmcnt(0) in the loop.
// RSCALE: bias[col] * (float)rs[row]   (deg-scaled bias for agg GEMM)
// ---------------------------------------------------------------------------
template<int ACT, int RSCALE>
__global__ __launch_bounds__(256) void gemm_kernel(
    const unsigned short* __restrict__ A, int lda,
    const unsigned short* __restrict__ B, int ldb, int K,
    const float* __restrict__ bias,
    const int* __restrict__ rs,
    unsigned short* __restrict__ C, int ldc)
{
  __shared__ alignas(16) unsigned short As[2][4096];   // 2 x (128 rows x 32 k)
  __shared__ alignas(16) unsigned short Bs[2][4096];
  int t = threadIdx.x, wave = t >> 6, lane = t & 63;
  int m0 = blockIdx.x * 128, n0 = blockIdx.y * 128;
  int wr = wave >> 1, wc = wave & 1;                // 2x2 wave grid

  f32x4 acc[4][4] = {};                             // [m][n]

  int srow = lane & 15, schunk = lane >> 4;
  const unsigned short* Ap0 = A + (size_t)(m0 + wave * 16 + srow) * lda + schunk * 8;
  const unsigned short* Ap1 = Ap0 + (size_t)64 * lda;
  const unsigned short* Bp0 = B + (size_t)(n0 + wave * 16 + srow) * ldb + schunk * 8;
  const unsigned short* Bp1 = Bp0 + (size_t)64 * ldb;

  auto stage = [&](int b, int kt){
    async16(Ap0 + kt, &As[b][(wave)     << 9]);
    async16(Ap1 + kt, &As[b][(wave + 4) << 9]);
    async16(Bp0 + kt, &Bs[b][(wave)     << 9]);
    async16(Bp1 + kt, &Bs[b][(wave + 4) << 9]);
  };
  int fo = (schunk << 7) + (srow << 3);
  auto compute = [&](int b){
    bf16x8 av[4], bv[4];
#pragma unroll
    for (int m = 0; m < 4; ++m) av[m] = *(const bf16x8*)&As[b][((wr * 4 + m) << 9) + fo];
#pragma unroll
    for (int n = 0; n < 4; ++n) bv[n] = *(const bf16x8*)&Bs[b][((wc * 4 + n) << 9) + fo];
#pragma unroll
    for (int m = 0; m < 4; ++m)
#pragma unroll
      for (int n = 0; n < 4; ++n)
        acc[m][n] = __builtin_amdgcn_mfma_f32_16x16x32_bf16(av[m], bv[n], acc[m][n], 0, 0, 0);
  };

  stage(0, 0);
  asm volatile("s_waitcnt vmcnt(0)" ::: "memory");
  __builtin_amdgcn_s_barrier();
  int cur = 0;
  for (int kt = 32; kt < K; kt += 32){
    stage(cur ^ 1, kt);                              // 4 DMAs fly during MFMA
    asm volatile("s_waitcnt vmcnt(4)" ::: "memory"); // prev tile's 4 done
    __builtin_amdgcn_sched_barrier(0);
    __builtin_amdgcn_s_barrier();
    compute(cur);
    asm volatile("s_waitcnt lgkmcnt(0)" ::: "memory");
    __builtin_amdgcn_s_barrier();
    cur ^= 1;
  }
  asm volatile("s_waitcnt vmcnt(0)" ::: "memory");   // last tile's loads
  __builtin_amdgcn_sched_barrier(0);
  __builtin_amdgcn_s_barrier();
  compute(cur);

  int coll = lane & 15, rq = lane >> 4;
#pragma unroll
  for (int n = 0; n < 4; ++n){
    int col = n0 + wc * 64 + n * 16 + coll;
    float bv = bias[col];
#pragma unroll
    for (int m = 0; m < 4; ++m){
#pragma unroll
      for (int r = 0; r < 4; ++r){
        int rrow = m0 + wr * 64 + m * 16 + rq * 4 + r;
        float scale = RSCALE ? (float)rs[rrow] : 1.0f;
        float v = acc[m][n][r] + bv * scale;
        if (ACT) v = fmaxf(v, 0.f);
        C[(size_t)rrow * ldc + col] = f2b(v);
      }
    }
  }
}

// ---------------------------------------------------------------------------
// gates = [x|h0] @ [w_ih|w_hh]^T + b ; LSTM elementwise fused in registers.
// 64 rows x 64 cols x 4 gates per block; counted-vmcnt double-buffered.
// ---------------------------------------------------------------------------
__global__ __launch_bounds__(256) void gates_lstm_kernel(
    const unsigned short* __restrict__ Xb,   // [N,256] bf16
    const unsigned short* __restrict__ H0b,  // [N,256] bf16
    const unsigned short* __restrict__ Wih,  // [1024][256] bf16
    const unsigned short* __restrict__ Whh,  // [1024][256] bf16
    const float* __restrict__ b_ih, const float* __restrict__ b_hh,
    const float* __restrict__ c0,            // [N,256] fp32
    float* __restrict__ h1o, float* __restrict__ c1o,  // fp32 outputs
    unsigned short* __restrict__ rb)         // relu(h1) bf16 [N,256]
{
  __shared__ alignas(16) unsigned short As[2][2048];
  __shared__ alignas(16) unsigned short Bs[2][4][2048];
  int t = threadIdx.x, wave = t >> 6, lane = t & 63;
  int m0 = blockIdx.x * 64, cb = blockIdx.y * 64;
  int srow = lane & 15, schunk = lane >> 4;

  f32x4 acc[4][4] = {};

  auto stage = [&](int b, int kt){
    const unsigned short* Abase = (kt < 256) ? (Xb + kt) : (H0b + (kt - 256));
    const unsigned short* Wbase = (kt < 256) ? (Wih + kt) : (Whh + (kt - 256));
    async16(Abase + (size_t)(m0 + wave * 16 + srow) * 256 + schunk * 8, &As[b][wave << 9]);
#pragma unroll
    for (int g = 0; g < 4; ++g)
      async16(Wbase + (size_t)(g * 256 + cb + wave * 16 + srow) * 256 + schunk * 8,
              &Bs[b][g][wave << 9]);
  };
  int fo = (schunk << 7) + (srow << 3);
  auto compute = [&](int b){
    bf16x8 a = *(const bf16x8*)&As[b][(wave << 9) + fo];
#pragma unroll
    for (int g = 0; g < 4; ++g){
#pragma unroll
      for (int j = 0; j < 4; ++j){
        bf16x8 bb = *(const bf16x8*)&Bs[b][g][(j << 9) + fo];
        acc[g][j] = __builtin_amdgcn_mfma_f32_16x16x32_bf16(a, bb, acc[g][j], 0, 0, 0);
      }
    }
  };

  stage(0, 0);
  asm volatile("s_waitcnt vmcnt(0)" ::: "memory");
  __builtin_amdgcn_s_barrier();
  int cur = 0;
  for (int kt = 32; kt < 512; kt += 32){
    stage(cur ^ 1, kt);                              // 5 DMAs fly during MFMA
    asm volatile("s_waitcnt vmcnt(5)" ::: "memory"); // prev tile's 5 done
    __builtin_amdgcn_sched_barrier(0);
    __builtin_amdgcn_s_barrier();
    compute(cur);
    asm volatile("s_waitcnt lgkmcnt(0)" ::: "memory");
    __builtin_amdgcn_s_barrier();
    cur ^= 1;
  }
  asm volatile("s_waitcnt vmcnt(0)" ::: "memory");
  __builtin_amdgcn_sched_barrier(0);
  __builtin_amdgcn_s_barrier();
  compute(cur);

  int coll = lane & 15, rq = lane >> 4;
#pragma unroll
  for (int j = 0; j < 4; ++j){
    int col = cb + j * 16 + coll;
    float bi  = b_ih[col]       + b_hh[col];
    float bff = b_ih[256 + col] + b_hh[256 + col];
    float bg  = b_ih[512 + col] + b_hh[512 + col];
    float bo  = b_ih[768 + col] + b_hh[768 + col];
#pragma unroll
    for (int r = 0; r < 4; ++r){
      int node = m0 + wave * 16 + rq * 4 + r;
      size_t off = (size_t)node * 256 + col;
      float iv = sigm(acc[0][j][r] + bi);
      float fv = sigm(acc[1][j][r] + bff);
      float gv = tanhf(acc[2][j][r] + bg);
      float ov = sigm(acc[3][j][r] + bo);
      float cv = fv * c0[off] + iv * gv;
      float hv = ov * tanhf(cv);
      h1o[off] = hv;
      c1o[off] = cv;
      rb[off] = f2b(fmaxf(hv, 0.f));
    }
  }
}

// ---------------------------------------------------------------------------
// counting sort by dst: hist -> scan -> scatter
// ---------------------------------------------------------------------------
__global__ __launch_bounds__(256) void hist_kernel(
    const int* __restrict__ dst, int* __restrict__ hist)
{
  int e = blockIdx.x * 256 + threadIdx.x;
  atomicAdd(&hist[dst[e]], 1);
}

__global__ __launch_bounds__(256) void scan1_kernel(
    const int* __restrict__ hist, int* __restrict__ offs, int* __restrict__ bsum)
{
  __shared__ int s[256];
  int b = blockIdx.x, t = threadIdx.x;
  int v = hist[b * 256 + t];
  s[t] = v; __syncthreads();
  for (int d = 1; d < 256; d <<= 1){
    int x = (t >= d) ? s[t - d] : 0;
    __syncthreads();
    s[t] += x;
    __syncthreads();
  }
  offs[b * 256 + t] = s[t] - v;
  if (t == 255) bsum[b] = s[255];
}

__global__ __launch_bounds__(256) void scan2_kernel(int* __restrict__ bsum){
  __shared__ int s[256];
  int t = threadIdx.x;
  int v = bsum[t];
  s[t] = v; __syncthreads();
  for (int d = 1; d < 256; d <<= 1){
    int x = (t >= d) ? s[t - d] : 0;
    __syncthreads();
    s[t] += x;
    __syncthreads();
  }
  bsum[t] = s[t] - v;
}

__global__ __launch_bounds__(256) void scan3_kernel(
    int* __restrict__ offs, const int* __restrict__ bsum, int* __restrict__ cursor)
{
  int i = blockIdx.x * 256 + threadIdx.x;
  int v = offs[i] + bsum[blockIdx.x];
  offs[i] = v;
  cursor[i] = v;
}

__global__ __launch_bounds__(256) void scatter_kernel(
    const int* __restrict__ src, const int* __restrict__ dst,
    int* __restrict__ cursor, int* __restrict__ sorted_src)
{
  int e = blockIdx.x * 256 + threadIdx.x;
  int d = dst[e];
  int pos = atomicAdd(&cursor[d], 1);
  sorted_src[pos] = src[e];
}

// ---------------------------------------------------------------------------
// per-node edge aggregation: Hsum[n] = sum_{e in edges(n)} relu(P[src_e]+Q[n])
// one wave per node, 4 dims/lane. No atomics; src rows graph-local (L2-hot).
// ---------------------------------------------------------------------------
__global__ __launch_bounds__(256) void edge_agg_kernel(
    const unsigned short* __restrict__ P,    // [N,256] bf16
    const unsigned short* __restrict__ Q,    // [N,256] bf16 (bias folded in)
    const int* __restrict__ sorted_src,
    const int* __restrict__ offs,
    const int* __restrict__ cnt,
    unsigned short* __restrict__ Hsum)       // [N,256] bf16
{
  int t = threadIdx.x;
  int n = (blockIdx.x << 2) + (t >> 6);
  int lane = t & 63;
  int d0 = lane * 4;
  int off = offs[n], c = cnt[n];
  ushort4 qv = *(const ushort4*)&Q[(size_t)n * 256 + d0];
  float q0 = bf2f(qv.x), q1 = bf2f(qv.y), q2 = bf2f(qv.z), q3 = bf2f(qv.w);
  float a0 = 0.f, a1 = 0.f, a2 = 0.f, a3 = 0.f;
  for (int i = 0; i < c; ++i){
    int s = sorted_src[off + i];
    ushort4 pv = *(const ushort4*)&P[(size_t)s * 256 + d0];
    a0 += fmaxf(bf2f(pv.x) + q0, 0.f);
    a1 += fmaxf(bf2f(pv.y) + q1, 0.f);
    a2 += fmaxf(bf2f(pv.z) + q2, 0.f);
    a3 += fmaxf(bf2f(pv.w) + q3, 0.f);
  }
  ushort4 o; o.x = f2b(a0); o.y = f2b(a1); o.z = f2b(a2); o.w = f2b(a3);
  *(ushort4*)&Hsum[(size_t)n * 256 + d0] = o;
}

// ---------------------------------------------------------------------------
// readout layer 2: logits[N,8] = rh[N,256] @ wr2[8,256]^T + br2  (fp32 out)
// ---------------------------------------------------------------------------
__global__ __launch_bounds__(256) void logits_kernel(
    const unsigned short* __restrict__ rh,
    const unsigned short* __restrict__ wr2b,
    const float* __restrict__ br2,
    float* __restrict__ out)
{
  __shared__ alignas(16) unsigned short W[2048];
  int t = threadIdx.x;
  *(uint4*)&W[t * 8] = *(const uint4*)&wr2b[t * 8];
  __syncthreads();
  int node = blockIdx.x * 32 + (t >> 3);
  int o = t & 7;
  const unsigned short* r = rh + (size_t)node * 256;
  float s = br2[o];
#pragma unroll
  for (int k = 0; k < 256; k += 8){
    uint4 av = *(const uint4*)&r[k];
    const unsigned short* ap = (const unsigned short*)&av;
#pragma unroll
    for (int i = 0; i < 8; ++i) s += bf2f(ap[i]) * bf2f(W[o * 256 + k + i]);
  }
  out[(size_t)node * 8 + o] = s;
}

// ---------------------------------------------------------------------------
extern "C" void kernel_launch(void* const* d_in, const int* in_sizes, int n_in,
                              void* d_out, int out_size, void* d_ws, size_t ws_size,
                              hipStream_t stream)
{
  (void)in_sizes; (void)n_in; (void)out_size; (void)ws_size;
  const float* obs = (const float*)d_in[0];
  const float* h0  = (const float*)d_in[1];
  const float* c0  = (const float*)d_in[2];
  const int*   src = (const int*)d_in[3];
  const int*   dst = (const int*)d_in[4];
  const float* w1a = (const float*)d_in[5];
  const float* b1a = (const float*)d_in[6];
  const float* w1b = (const float*)d_in[7];
  const float* b1b = (const float*)d_in[8];
  const float* wih = (const float*)d_in[9];
  const float* bih = (const float*)d_in[10];
  const float* whh = (const float*)d_in[11];
  const float* bhh = (const float*)d_in[12];
  const float* w1  = (const float*)d_in[13];
  const float* b1  = (const float*)d_in[14];
  const float* we  = (const float*)d_in[15];
  const float* be  = (const float*)d_in[16];
  const float* we2 = (const float*)d_in[17];
  const float* be2 = (const float*)d_in[18];
  const float* wn  = (const float*)d_in[19];
  const float* bn  = (const float*)d_in[20];
  const float* wn2 = (const float*)d_in[21];
  const float* bn2 = (const float*)d_in[22];
  const float* wr  = (const float*)d_in[23];
  const float* br  = (const float*)d_in[24];
  const float* wr2 = (const float*)d_in[25];
  const float* br2 = (const float*)d_in[26];

  char* ws = (char*)d_ws;
  typedef unsigned short u16;
  // bf16 weight copies + sort scratch
  u16* w1a_b = (u16*)(ws + 0);
  u16* w1b_b = (u16*)(ws + 262144);
  u16* wih_b = (u16*)(ws + 524288);
  u16* whh_b = (u16*)(ws + 1048576);
  u16* w1_b  = (u16*)(ws + 1572864);
  u16* we_b  = (u16*)(ws + 1638400);
  u16* we2_b = (u16*)(ws + 1769472);
  u16* wn_b  = (u16*)(ws + 1835008);
  u16* wn2_b = (u16*)(ws + 1966080);
  u16* wr_b  = (u16*)(ws + 2031616);
  u16* wr2_b = (u16*)(ws + 2097152);
  float* zbias = (float*)(ws + 2101248);        // 512 fp32 zeros
  int* hist    = (int*)(ws + 2103296);          // [65536] = deg
  int* offs    = (int*)(ws + 2365440);          // [65536]
  int* cursor  = (int*)(ws + 2627584);          // [65536]
  int* bsum    = (int*)(ws + 2889728);          // [256]
  int* ssrc    = (int*)(ws + 2890752);          // sorted_src [524288]

  // aliased activation regions
  char* RA = ws + 5242880;    // 33.5MB: obs_b -> x_b -> P -> nf2
  char* RB = ws + 38797312;   // 33.5MB: h0_b -> Hsum -> hidn -> rh
  char* RY = ws + 72351744;   // 67MB:   y1 -> [rb->Q | ninp]

  u16* obs_b = (u16*)RA;
  u16* x_b   = (u16*)RA;
  u16* P     = (u16*)RA;
  u16* nf2   = (u16*)RA;
  u16* h0_b  = (u16*)RB;
  u16* Hsum  = (u16*)RB;
  u16* hidn  = (u16*)RB;
  u16* rh    = (u16*)RB;
  u16* y1    = (u16*)RY;
  u16* rb    = (u16*)RY;
  u16* Q     = (u16*)RY;
  u16* ninp  = (u16*)(RY + 33554432);

  float* logits = (float*)d_out;
  float* h1o = logits + (size_t)NN * 8;
  float* c1o = h1o + (size_t)NN * 256;

  // 0) zero-init scratch
  (void)hipMemsetAsync(zbias, 0, 2048, stream);
  (void)hipMemsetAsync(hist, 0, 65536 * 4, stream);

  // 1) convert fp32 -> bf16
  ConvArgs ca;
  const float* ss[13] = {obs, h0, w1a, w1b, wih, whh, w1, we, we2, wn, wn2, wr, wr2};
  u16* dd[13] = {obs_b, h0_b, w1a_b, w1b_b, wih_b, whh_b, w1_b, we_b, we2_b, wn_b, wn2_b, wr_b, wr2_b};
  int nn[13] = {NN*256, NN*256, 512*256, 256*512, 1024*256, 1024*256, 128*256,
                256*256, 128*256, 256*256, 128*256, 256*128, 8*256};
  for (int i = 0; i < 13; ++i){ ca.s[i]=ss[i]; ca.d[i]=dd[i]; ca.n4[i]=nn[i]/4; }
  ca.cnt = 13;
  convert_kernel<<<2048, 256, 0, stream>>>(ca);

  // 2) counting sort of edges by dst (independent of GEMM chain)
  hist_kernel<<<NE/256, 256, 0, stream>>>(dst, hist);
  scan1_kernel<<<256, 256, 0, stream>>>(hist, offs, bsum);
  scan2_kernel<<<1, 256, 0, stream>>>(bsum);
  scan3_kernel<<<256, 256, 0, stream>>>(offs, bsum, cursor);
  scatter_kernel<<<NE/256, 256, 0, stream>>>(src, dst, cursor, ssrc);

  // 3) y1 = relu(obs @ w1a^T + b1a)   [N,512]
  gemm_kernel<1,0><<<dim3(NN/128, 4), 256, 0, stream>>>(obs_b, 256, w1a_b, 256, 256, b1a, nullptr, y1, 512);
  // 4) x = y1 @ w1b^T + b1b           [N,256]
  gemm_kernel<0,0><<<dim3(NN/128, 2), 256, 0, stream>>>(y1, 512, w1b_b, 512, 512, b1b, nullptr, x_b, 256);
  // 5) gates + LSTM fused -> h1, c1 (fp32 out), rb = relu(h1) bf16
  gates_lstm_kernel<<<dim3(NN/64, 4), 256, 0, stream>>>(
      x_b, h0_b, wih_b, whh_b, bih, bhh, c0, h1o, c1o, rb);
  // 6) nf = rb @ w1^T + b1 -> ninp cols 0..127 (ldc=256)
  gemm_kernel<0,0><<<dim3(NN/128, 1), 256, 0, stream>>>(rb, 256, w1_b, 256, 256, b1, nullptr, ninp, 256);
  // 7) P = nf @ we_L^T (zero bias)    [N,256], K=128
  gemm_kernel<0,0><<<dim3(NN/128, 2), 256, 0, stream>>>(ninp, 256, we_b, 256, 128, zbias, nullptr, P, 256);
  // 8) Q = nf @ we_R^T + be           [N,256], K=128
  gemm_kernel<0,0><<<dim3(NN/128, 2), 256, 0, stream>>>(ninp, 256, we_b + 128, 256, 128, be, nullptr, Q, 256);
  // 9) Hsum[n] = sum over edges relu(P[src]+Q[n])
  edge_agg_kernel<<<NN/4, 256, 0, stream>>>(P, Q, ssrc, offs, hist, Hsum);
  // 10) agg = Hsum @ we2^T + deg*be2 -> ninp cols 128..255
  gemm_kernel<0,1><<<dim3(NN/128, 1), 256, 0, stream>>>(Hsum, 256, we2_b, 256, 256, be2, hist, ninp + 128, 256);
  // 11) hidn = relu(ninp @ wn^T + bn)  [N,256]
  gemm_kernel<1,0><<<dim3(NN/128, 2), 256, 0, stream>>>(ninp, 256, wn_b, 256, 256, bn, nullptr, hidn, 256);
  // 12) nf2 = hidn @ wn2^T + bn2       [N,128]
  gemm_kernel<0,0><<<dim3(NN/128, 1), 256, 0, stream>>>(hidn, 256, wn2_b, 256, 256, bn2, nullptr, nf2, 128);
  // 13) rh = relu(nf2 @ wr^T + br)     [N,256]
  gemm_kernel<1,0><<<dim3(NN/128, 2), 256, 0, stream>>>(nf2, 128, wr_b, 128, 128, br, nullptr, rh, 256);
  // 14) logits = rh @ wr2^T + br2      [N,8] fp32
  logits_kernel<<<NN/32, 256, 0, stream>>>(rh, wr2_b, br2, logits);
}